// Round 7
// baseline (156.329 us; speedup 1.0000x reference)
//
#include <hip/hip_runtime.h>

#define N_ 2048
#define BN 16384
#define IN_DIM 320
#define QKV_N 1536
// (1/sqrt(320)) * log2(e): folded into Q so QK^T scores are base-2 exponents
#define ALPHA 0.08064911f

typedef float f32x4 __attribute__((ext_vector_type(4)));
typedef short v8s __attribute__((ext_vector_type(8)));
typedef unsigned int u32x2 __attribute__((ext_vector_type(2)));

__device__ __forceinline__ short f2b(float f) {
  unsigned u = __builtin_bit_cast(unsigned, f);
  u = u + 0x7fff + ((u >> 16) & 1);
  return (short)(u >> 16);
}

__device__ __forceinline__ void gload16(const short* g, void* l) {
  __builtin_amdgcn_global_load_lds((const __attribute__((address_space(1))) void*)g,
                                   (__attribute__((address_space(3))) void*)l, 16, 0, 0);
}

// pi permutation of kv within a 64-tile (matches S^T lane layout -> PV A-frag slots)
__device__ __forceinline__ int piperm(int t) {
  return ((t >> 5) & 1) * 32 + ((t >> 2) & 3) * 8 + ((t >> 4) & 1) * 4 + (t & 3);
}

// ---------------- Kernel 1: build x = [data | mask | time-embedding] ----------------
__global__ void build_x(const float* __restrict__ times, const float* __restrict__ data,
                        const float* __restrict__ maskv, const float* __restrict__ w_per,
                        const float* __restrict__ b_per, const float* __restrict__ w_lin,
                        const float* __restrict__ b_lin, short* __restrict__ x) {
  int row = blockIdx.x;       // 0..16383
  int t = threadIdx.x;        // 128 threads
  float tt = times[row];
  short* xr = x + (size_t)row * IN_DIM;
  const float* dr = data + (size_t)row * 96;
  const float* mr = maskv + (size_t)row * 96;
  if (t < 96) { xr[t] = f2b(dr[t]); xr[96 + t] = f2b(mr[t]); }
  float val;
  if (t == 0) val = tt * w_lin[0] + b_lin[0];
  else        val = __sinf(tt * w_per[t - 1] + b_per[t - 1]);
  xr[192 + t] = f2b(val);
}

// ---------------- Kernel 2: transpose weights (fp32 -> bf16) ----------------
__global__ void transpose_w(const float* __restrict__ Wq, const float* __restrict__ Wk,
                            const float* __restrict__ Wv, const float* __restrict__ Wfc,
                            short* __restrict__ Wt, short* __restrict__ WfcT) {
  int idx = blockIdx.x * 256 + threadIdx.x;
  if (idx < QKV_N * IN_DIM) {
    int n = idx / IN_DIM, kk = idx - n * IN_DIM;
    const float* W = (n < 512) ? Wq : (n < 1024 ? Wk : Wv);
    Wt[idx] = f2b(W[(size_t)kk * 512 + (n & 511)]);
  } else {
    int j = idx - QKV_N * IN_DIM;   // 0..32767
    int d = j >> 9, kk = j & 511;
    WfcT[j] = f2b(Wfc[kk * 64 + d]);
  }
}

// ---------------- Kernel 3: QKV GEMM (M=16384, N=1536, K=320) ----------------
__launch_bounds__(256)
__global__ void qkv_gemm(const short* __restrict__ x, const short* __restrict__ Wt,
                         const float* __restrict__ bq, const float* __restrict__ bk,
                         const float* __restrict__ bv, const int* __restrict__ exist,
                         short* __restrict__ q, short* __restrict__ k, short* __restrict__ vtb) {
  __shared__ short As[128][40];
  __shared__ short Bs[128][40];
  int bm = blockIdx.x;   // 0..127
  int bn = blockIdx.y;   // 0..11
  int tid = threadIdx.x, wave = tid >> 6, lane = tid & 63;
  int wm = wave >> 1, wn = wave & 1;
  int l16 = lane & 15, lh = lane >> 4;
  f32x4 acc[4][4] = {};
  for (int kt = 0; kt < 10; ++kt) {
    int k0 = kt * 32;
#pragma unroll
    for (int s = 0; s < 2; ++s) {
      int c = tid + s * 256;          // 512 16B-chunks
      int r = c >> 2, c8 = c & 3;
      *(v8s*)&As[r][c8 * 8] = *(const v8s*)&x[(size_t)(bm * 128 + r) * IN_DIM + k0 + c8 * 8];
      *(v8s*)&Bs[r][c8 * 8] = *(const v8s*)&Wt[(size_t)(bn * 128 + r) * IN_DIM + k0 + c8 * 8];
    }
    __syncthreads();
    v8s af[4], bfr[4];
#pragma unroll
    for (int m = 0; m < 4; ++m) af[m] = *(const v8s*)&As[wm * 64 + m * 16 + l16][lh * 8];
#pragma unroll
    for (int n = 0; n < 4; ++n) bfr[n] = *(const v8s*)&Bs[wn * 64 + n * 16 + l16][lh * 8];
#pragma unroll
    for (int m = 0; m < 4; ++m)
#pragma unroll
      for (int n = 0; n < 4; ++n)
        acc[m][n] = __builtin_amdgcn_mfma_f32_16x16x32_bf16(af[m], bfr[n], acc[m][n], 0, 0, 0);
    __syncthreads();
  }
  int w = bn >> 2;   // 0:q 1:k 2:v (uniform per block)
  if (w < 2) {
    // q/k -> [bh][n][d] straight
#pragma unroll
    for (int m = 0; m < 4; ++m) {
      int row0 = bm * 128 + wm * 64 + m * 16 + lh * 4;
#pragma unroll
      for (int n = 0; n < 4; ++n) {
        int col = bn * 128 + wn * 64 + n * 16 + l16;
        int c = col & 511;
        float bb = (w == 0) ? bq[c] : bk[c];
        int h = c >> 6, d = c & 63;
#pragma unroll
        for (int r = 0; r < 4; ++r) {
          int rr = row0 + r;
          int b = rr >> 11, ntok = rr & 2047;
          float val = acc[m][n][r] + bb;
          if (w == 0) q[(((size_t)(b * 8 + h) * N_ + ntok) << 6) + d] = f2b(val * ALPHA);
          else        k[(((size_t)(b * 8 + h) * N_ + ntok) << 6) + d] = f2b(val);
        }
      }
    }
  } else {
    // v -> transposed+pi-permuted [bh][d][2048], mask-zeroed, packed 8B stores
#pragma unroll
    for (int m = 0; m < 4; ++m) {
      int row0 = bm * 128 + wm * 64 + m * 16 + lh * 4;
      float fl[4];
#pragma unroll
      for (int r = 0; r < 4; ++r) fl[r] = (exist[row0 + r] != 0) ? 1.f : 0.f;
      int b = row0 >> 11, ntok0 = row0 & 2047;
      int colbase = (ntok0 & ~63) | piperm(ntok0 & 63);   // r adds 0..3 consecutively
#pragma unroll
      for (int n = 0; n < 4; ++n) {
        int c = (bn * 128 + wn * 64 + n * 16 + l16) & 511;
        float bb = bv[c];
        int h = c >> 6, d = c & 63;
        float v0 = (acc[m][n][0] + bb) * fl[0];
        float v1 = (acc[m][n][1] + bb) * fl[1];
        float v2 = (acc[m][n][2] + bb) * fl[2];
        float v3 = (acc[m][n][3] + bb) * fl[3];
        uint lopk, hipk;
        asm("v_cvt_pk_bf16_f32 %0, %1, %2" : "=v"(lopk) : "v"(v0), "v"(v1));
        asm("v_cvt_pk_bf16_f32 %0, %1, %2" : "=v"(hipk) : "v"(v2), "v"(v3));
        u32x2 pk2 = {lopk, hipk};
        *(u32x2*)&vtb[(((size_t)((b * 8 + h) * 64 + d)) << 11) + colbase] = pk2;
      }
    }
  }
}

// --- Kernel 4: flash attention (swapped QK^T, in-reg P, 64q/wave, counted-vmcnt pipe) ---
__launch_bounds__(256, 2)
__global__ void attn_kernel(const short* __restrict__ q, const short* __restrict__ k,
                            const short* __restrict__ vt, const int* __restrict__ exist,
                            short* __restrict__ att) {
  __shared__ short Ks[2][64][64];    // Ks[buf][r][c]: chunk c holds global chunk c^(r&7)
  __shared__ short VTs[2][64][64];   // VTs[buf][d][c]: pi-permuted cols, same swizzle
  __shared__ short flags[2048];      // bf16 mask flag, pi-permuted per 64-tile (whole seq)
  // XCD swizzle: all 8 q-blocks of one (b,h) land on the same XCD (id mod 8)
  int bx = blockIdx.x;                      // 0..511
  int bh = ((bx >> 6) << 3) | (bx & 7);     // 0..63
  int q0 = ((bx >> 3) & 7) * 256;
  int b = bh >> 3, h = bh & 7;
  int tid = threadIdx.x, wave = tid >> 6, lane = tid & 63;
  int l16 = lane & 15, lh = lane >> 4;
  const short* qp = q + (size_t)bh * N_ * 64;
  const short* kp = k + (size_t)bh * N_ * 64;
  const short* vp = vt + (size_t)bh * N_ * 64;   // [64][2048]
  const int* ex = exist + b * N_;
  v8s qf[4][2];
#pragma unroll
  for (int m = 0; m < 4; ++m)
#pragma unroll
    for (int kc = 0; kc < 2; ++kc)
      qf[m][kc] = *(const v8s*)&qp[(size_t)(q0 + wave * 64 + m * 16 + l16) * 64 + kc * 32 + lh * 8];
  f32x4 oacc[4][4] = {};
  f32x4 lacc[4] = {};
  const f32x4 zf = {0.f, 0.f, 0.f, 0.f};
  // staging geometry: lane covers LDS bytes (s*4096 + wave*1024 + lane*16)
  int srow = wave * 8 + (lane >> 3);   // + s*32
  int scol = lane & 7;
  auto stage = [&](int buf, int kv0) {
#pragma unroll
    for (int s = 0; s < 2; ++s) {
      int r = s * 32 + srow;
      int cs = (scol ^ (r & 7)) * 8;
      gload16(kp + (size_t)(kv0 + r) * 64 + cs, (char*)&Ks[buf][0][0] + s * 4096 + wave * 1024);
      gload16(vp + ((size_t)r << 11) + kv0 + cs, (char*)&VTs[buf][0][0] + s * 4096 + wave * 1024);
    }
  };
  // one-time: mask flags for the whole sequence (pi-permuted, bf16)
  stage(0, 0);
#pragma unroll
  for (int j = 0; j < 8; ++j) {
    int i = tid * 8 + j;
    flags[(i & ~63) | piperm(i & 63)] = (ex[i] != 0) ? (short)0x3F80 : (short)0;
  }
  __syncthreads();   // drains prologue stage + flags
#pragma unroll 1
  for (int kt = 0; kt < 32; ++kt) {
    int cur = kt & 1;
    int kv0 = kt << 6;
    if (kt < 31) stage(cur ^ 1, kv0 + 64);           // prefetch next tile (stays in flight)
    if (kt > 0) {
      if (kt < 31) asm volatile("s_waitcnt vmcnt(4)" ::: "memory");  // own cur-tile loads done
      else         asm volatile("s_waitcnt vmcnt(0)" ::: "memory");
      __builtin_amdgcn_s_barrier();                  // all waves' cur-tile data in LDS
      __builtin_amdgcn_sched_barrier(0);
    }
    // ---- K fragments (shared across all m) ----
    v8s kf[8];
#pragma unroll
    for (int kc = 0; kc < 2; ++kc)
#pragma unroll
      for (int n = 0; n < 4; ++n) {
        int krow = n * 16 + l16;
        kf[kc * 4 + n] = *(const v8s*)&Ks[cur][krow][((kc * 4 + lh) ^ (krow & 7)) * 8];
      }
    // ---- S^T = K @ Q in m-halves; p = 2^s -> PV A-fragments in-register ----
    v8s pf[4][2];
#pragma unroll
    for (int mh = 0; mh < 2; ++mh) {
      f32x4 sacc[2][4];
#pragma unroll
      for (int n = 0; n < 4; ++n)
#pragma unroll
        for (int mm = 0; mm < 2; ++mm) {
          sacc[mm][n] = __builtin_amdgcn_mfma_f32_16x16x32_bf16(kf[n], qf[mh * 2 + mm][0], zf, 0, 0, 0);
          sacc[mm][n] = __builtin_amdgcn_mfma_f32_16x16x32_bf16(kf[4 + n], qf[mh * 2 + mm][1], sacc[mm][n], 0, 0, 0);
        }
#pragma unroll
      for (int mm = 0; mm < 2; ++mm)
#pragma unroll
        for (int kc = 0; kc < 2; ++kc)
#pragma unroll
          for (int half = 0; half < 2; ++half) {
            int n = kc * 2 + half;
            float p0 = exp2f(sacc[mm][n][0]);
            float p1 = exp2f(sacc[mm][n][1]);
            float p2 = exp2f(sacc[mm][n][2]);
            float p3 = exp2f(sacc[mm][n][3]);
            uint w0, w1;
            asm("v_cvt_pk_bf16_f32 %0, %1, %2" : "=v"(w0) : "v"(p0), "v"(p1));
            asm("v_cvt_pk_bf16_f32 %0, %1, %2" : "=v"(w1) : "v"(p2), "v"(p3));
            ((uint*)&pf[mh * 2 + mm][kc])[half * 2]     = w0;
            ((uint*)&pf[mh * 2 + mm][kc])[half * 2 + 1] = w1;
          }
    }
    // ---- O += P @ V ; l += P @ flag (masking via zeroed V rows + flag frag) ----
#pragma unroll
    for (int kc = 0; kc < 2; ++kc) {
      v8s ff = *(const v8s*)&flags[kv0 + kc * 32 + lh * 8];
#pragma unroll
      for (int m = 0; m < 4; ++m)
        lacc[m] = __builtin_amdgcn_mfma_f32_16x16x32_bf16(pf[m][kc], ff, lacc[m], 0, 0, 0);
#pragma unroll
      for (int n = 0; n < 4; ++n) {
        int vrow = n * 16 + l16;
        v8s vf = *(const v8s*)&VTs[cur][vrow][((kc * 4 + lh) ^ (vrow & 7)) * 8];
#pragma unroll
        for (int m = 0; m < 4; ++m)
          oacc[m][n] = __builtin_amdgcn_mfma_f32_16x16x32_bf16(pf[m][kc], vf, oacc[m][n], 0, 0, 0);
      }
    }
    __builtin_amdgcn_s_barrier();                    // reads of cur done before overwrite
    __builtin_amdgcn_sched_barrier(0);
  }
  // ---- epilogue: normalize, query-mask, write att[b][n][h*64+d] ----
#pragma unroll
  for (int m = 0; m < 4; ++m)
#pragma unroll
    for (int r = 0; r < 4; ++r) {
      int row = q0 + wave * 64 + m * 16 + lh * 4 + r;
      float qm = (ex[row] != 0) ? 1.f : 0.f;
      float inv = qm / fmaxf(lacc[m][r], 1e-20f);
#pragma unroll
      for (int n = 0; n < 4; ++n)
        att[((size_t)(b * N_ + row)) * 512 + h * 64 + n * 16 + l16] = f2b(oacc[m][n][r] * inv);
    }
}

// ---------------- Kernel 5: out = att @ Wfc + bfc (M=16384, N=64, K=512), fp32 out ----------
__launch_bounds__(256)
__global__ void out_gemm(const short* __restrict__ att, const short* __restrict__ WfcT,
                         const float* __restrict__ bfc, float* __restrict__ out) {
  __shared__ short As[128][40];
  __shared__ short Bs[64][40];
  int bm = blockIdx.x;
  int tid = threadIdx.x, wave = tid >> 6, lane = tid & 63;
  int l16 = lane & 15, lh = lane >> 4;
  f32x4 acc[2][4] = {};
  for (int kt = 0; kt < 16; ++kt) {
    int k0 = kt * 32;
#pragma unroll
    for (int s = 0; s < 2; ++s) {
      int c = tid + s * 256;
      int r = c >> 2, c8 = c & 3;
      *(v8s*)&As[r][c8 * 8] = *(const v8s*)&att[(size_t)(bm * 128 + r) * 512 + k0 + c8 * 8];
    }
    { int r = tid >> 2, c8 = tid & 3;
      if (r < 64) *(v8s*)&Bs[r][c8 * 8] = *(const v8s*)&WfcT[(size_t)r * 512 + k0 + c8 * 8]; }
    __syncthreads();
    v8s bfr[4];
#pragma unroll
    for (int n = 0; n < 4; ++n) bfr[n] = *(const v8s*)&Bs[n * 16 + l16][lh * 8];
#pragma unroll
    for (int m = 0; m < 2; ++m) {
      v8s af = *(const v8s*)&As[wave * 32 + m * 16 + l16][lh * 8];
#pragma unroll
      for (int n = 0; n < 4; ++n)
        acc[m][n] = __builtin_amdgcn_mfma_f32_16x16x32_bf16(af, bfr[n], acc[m][n], 0, 0, 0);
    }
    __syncthreads();
  }
#pragma unroll
  for (int m = 0; m < 2; ++m)
#pragma unroll
    for (int n = 0; n < 4; ++n) {
      float bb = bfc[n * 16 + l16];
#pragma unroll
      for (int r = 0; r < 4; ++r) {
        int row = bm * 128 + wave * 32 + m * 16 + lh * 4 + r;
        out[(size_t)row * 64 + n * 16 + l16] = acc[m][n][r] + bb;
      }
    }
}

extern "C" void kernel_launch(void* const* d_in, const int* in_sizes, int n_in,
                              void* d_out, int out_size, void* d_ws, size_t ws_size,
                              hipStream_t stream) {
  const float* times = (const float*)d_in[0];
  const float* data  = (const float*)d_in[1];
  const float* maskv = (const float*)d_in[2];
  const int*   exist = (const int*)d_in[3];
  const float* w_per = (const float*)d_in[4];
  const float* b_per = (const float*)d_in[5];
  const float* w_lin = (const float*)d_in[6];
  const float* b_lin = (const float*)d_in[7];
  const float* Wq  = (const float*)d_in[8];
  const float* bq  = (const float*)d_in[9];
  const float* Wk  = (const float*)d_in[10];
  const float* bk  = (const float*)d_in[11];
  const float* Wv  = (const float*)d_in[12];
  const float* bv  = (const float*)d_in[13];
  const float* Wfc = (const float*)d_in[14];
  const float* bfc = (const float*)d_in[15];
  float* out = (float*)d_out;

  char* ws = (char*)d_ws;
  short* x    = (short*)(ws);                    // 16384*320*2  = 10,485,760
  short* Wt   = (short*)(ws + 10485760);         // 1536*320*2   =    983,040
  short* WfcT = (short*)(ws + 11468800);         // 64*512*2     =     65,536
  short* qb   = (short*)(ws + 11534336);         // 64*2048*64*2 = 16,777,216
  short* kb   = (short*)(ws + 28311552);
  short* vtb  = (short*)(ws + 45088768);         // V^T pi-permuted, mask-zeroed [bh][64][2048]
  short* att  = (short*)(ws + 61865984);         // 16384*512*2  = 16,777,216

  build_x<<<BN, 128, 0, stream>>>(times, data, maskv, w_per, b_per, w_lin, b_lin, x);
  transpose_w<<<2048, 256, 0, stream>>>(Wq, Wk, Wv, Wfc, Wt, WfcT);
  qkv_gemm<<<dim3(128, 12), 256, 0, stream>>>(x, Wt, bq, bk, bv, exist, qb, kb, vtb);
  attn_kernel<<<512, 256, 0, stream>>>(qb, kb, vtb, exist, att);
  out_gemm<<<128, 256, 0, stream>>>(att, WfcT, bfc, out);
}

// Round 8
// 155.298 us; speedup vs baseline: 1.0066x; 1.0066x over previous
//
#include <hip/hip_runtime.h>

#define N_ 2048
#define BN 16384
#define IN_DIM 320
#define QKV_N 1536
// (1/sqrt(320)) * log2(e): folded into Q so QK^T scores are base-2 exponents
#define ALPHA 0.08064911f

typedef float f32x4 __attribute__((ext_vector_type(4)));
typedef short v8s __attribute__((ext_vector_type(8)));
typedef unsigned int u32x2 __attribute__((ext_vector_type(2)));

__device__ __forceinline__ short f2b(float f) {
  unsigned u = __builtin_bit_cast(unsigned, f);
  u = u + 0x7fff + ((u >> 16) & 1);
  return (short)(u >> 16);
}

// pi permutation of kv within a 64-tile (matches S^T lane layout -> PV A-frag slots)
__device__ __forceinline__ int piperm(int t) {
  return ((t >> 5) & 1) * 32 + ((t >> 2) & 3) * 8 + ((t >> 4) & 1) * 4 + (t & 3);
}

// ---------------- Kernel 1: build x = [data | mask | time-embedding] + mask flags ------
__global__ void build_x(const float* __restrict__ times, const float* __restrict__ data,
                        const float* __restrict__ maskv, const float* __restrict__ w_per,
                        const float* __restrict__ b_per, const float* __restrict__ w_lin,
                        const float* __restrict__ b_lin, const int* __restrict__ exist,
                        short* __restrict__ x, short* __restrict__ flagsg) {
  int row = blockIdx.x;       // 0..16383
  int t = threadIdx.x;        // 128 threads
  float tt = times[row];
  short* xr = x + (size_t)row * IN_DIM;
  const float* dr = data + (size_t)row * 96;
  const float* mr = maskv + (size_t)row * 96;
  if (t < 96) { xr[t] = f2b(dr[t]); xr[96 + t] = f2b(mr[t]); }
  float val;
  if (t == 0) {
    val = tt * w_lin[0] + b_lin[0];
    // bf16 mask flag at pi-permuted position (row&~63 preserves b*2048 + tile base)
    flagsg[(row & ~63) | piperm(row & 63)] = (exist[row] != 0) ? (short)0x3F80 : (short)0;
  } else {
    val = __sinf(tt * w_per[t - 1] + b_per[t - 1]);
  }
  xr[192 + t] = f2b(val);
}

// ---------------- Kernel 2: transpose weights (fp32 -> bf16) ----------------
__global__ void transpose_w(const float* __restrict__ Wq, const float* __restrict__ Wk,
                            const float* __restrict__ Wv, const float* __restrict__ Wfc,
                            short* __restrict__ Wt, short* __restrict__ WfcT) {
  int idx = blockIdx.x * 256 + threadIdx.x;
  if (idx < QKV_N * IN_DIM) {
    int n = idx / IN_DIM, kk = idx - n * IN_DIM;
    const float* W = (n < 512) ? Wq : (n < 1024 ? Wk : Wv);
    Wt[idx] = f2b(W[(size_t)kk * 512 + (n & 511)]);
  } else {
    int j = idx - QKV_N * IN_DIM;   // 0..32767
    int d = j >> 9, kk = j & 511;
    WfcT[j] = f2b(Wfc[kk * 64 + d]);
  }
}

// ---------------- Kernel 3: QKV GEMM (M=16384, N=1536, K=320) ----------------
// q -> [bh][n][d]; K -> fragment-major K'; V -> fragment-major V' (pi-permuted, masked)
__launch_bounds__(256)
__global__ void qkv_gemm(const short* __restrict__ x, const short* __restrict__ Wt,
                         const float* __restrict__ bq, const float* __restrict__ bk,
                         const float* __restrict__ bv, const int* __restrict__ exist,
                         short* __restrict__ q, short* __restrict__ kT, short* __restrict__ vT) {
  __shared__ short As[128][40];
  __shared__ short Bs[128][40];
  int bm = blockIdx.x;   // 0..127
  int bn = blockIdx.y;   // 0..11
  int tid = threadIdx.x, wave = tid >> 6, lane = tid & 63;
  int wm = wave >> 1, wn = wave & 1;
  int l16 = lane & 15, lh = lane >> 4;
  f32x4 acc[4][4] = {};
  for (int kt = 0; kt < 10; ++kt) {
    int k0 = kt * 32;
#pragma unroll
    for (int s = 0; s < 2; ++s) {
      int c = tid + s * 256;          // 512 16B-chunks
      int r = c >> 2, c8 = c & 3;
      *(v8s*)&As[r][c8 * 8] = *(const v8s*)&x[(size_t)(bm * 128 + r) * IN_DIM + k0 + c8 * 8];
      *(v8s*)&Bs[r][c8 * 8] = *(const v8s*)&Wt[(size_t)(bn * 128 + r) * IN_DIM + k0 + c8 * 8];
    }
    __syncthreads();
    v8s af[4], bfr[4];
#pragma unroll
    for (int m = 0; m < 4; ++m) af[m] = *(const v8s*)&As[wm * 64 + m * 16 + l16][lh * 8];
#pragma unroll
    for (int n = 0; n < 4; ++n) bfr[n] = *(const v8s*)&Bs[wn * 64 + n * 16 + l16][lh * 8];
#pragma unroll
    for (int m = 0; m < 4; ++m)
#pragma unroll
      for (int n = 0; n < 4; ++n)
        acc[m][n] = __builtin_amdgcn_mfma_f32_16x16x32_bf16(af[m], bfr[n], acc[m][n], 0, 0, 0);
    __syncthreads();
  }
  int w = bn >> 2;   // 0:q 1:k 2:v (uniform per block)
  if (w == 0) {
#pragma unroll
    for (int m = 0; m < 4; ++m) {
      int row0 = bm * 128 + wm * 64 + m * 16 + lh * 4;
#pragma unroll
      for (int n = 0; n < 4; ++n) {
        int c = (bn * 128 + wn * 64 + n * 16 + l16) & 511;
        float bb = bq[c];
        int h = c >> 6, d = c & 63;
#pragma unroll
        for (int r = 0; r < 4; ++r) {
          int rr = row0 + r;
          int b = rr >> 11, ntok = rr & 2047;
          q[(((size_t)(b * 8 + h) * N_ + ntok) << 6) + d] = f2b((acc[m][n][r] + bb) * ALPHA);
        }
      }
    }
  } else if (w == 1) {
    // K' fragment-major: [bh][kt][m(kv-blk)][kc][lh2][l16'][8]
    int ktile = (bm * 2 + wm) & 31;         // = ntok >> 6 (m-independent)
    int b = bm >> 4;
#pragma unroll
    for (int m = 0; m < 4; ++m) {
#pragma unroll
      for (int n = 0; n < 4; ++n) {
        int c = (bn * 128 + wn * 64 + n * 16 + l16) & 511;
        float bb = bk[c];
        int h = c >> 6;
        int d = n * 16 + l16;               // == c & 63
        int kc2 = d >> 5, lh2 = (d >> 3) & 3, j = d & 7;
        size_t base = (((((size_t)((b * 8 + h) * 32 + ktile)) * 4 + m) * 2 + kc2) * 4 + lh2) * 128 + j;
#pragma unroll
        for (int r = 0; r < 4; ++r)
          kT[base + (lh * 4 + r) * 8] = f2b(acc[m][n][r] + bb);
      }
    }
  } else {
    // V' fragment-major: [bh][kt][n(d-blk)][kc=m>>1][lh][l16][8], pi slot (m&1)*4+r, masked
    int ktile = (bm * 2 + wm) & 31;
    int b = bm >> 4;
#pragma unroll
    for (int m = 0; m < 4; ++m) {
      int row0 = bm * 128 + wm * 64 + m * 16 + lh * 4;
      float fl[4];
#pragma unroll
      for (int r = 0; r < 4; ++r) fl[r] = (exist[row0 + r] != 0) ? 1.f : 0.f;
#pragma unroll
      for (int n = 0; n < 4; ++n) {
        int c = (bn * 128 + wn * 64 + n * 16 + l16) & 511;
        float bb = bv[c];
        int h = c >> 6;
        float v0 = (acc[m][n][0] + bb) * fl[0];
        float v1 = (acc[m][n][1] + bb) * fl[1];
        float v2 = (acc[m][n][2] + bb) * fl[2];
        float v3 = (acc[m][n][3] + bb) * fl[3];
        uint lopk, hipk;
        asm("v_cvt_pk_bf16_f32 %0, %1, %2" : "=v"(lopk) : "v"(v0), "v"(v1));
        asm("v_cvt_pk_bf16_f32 %0, %1, %2" : "=v"(hipk) : "v"(v2), "v"(v3));
        u32x2 pk2 = {lopk, hipk};
        size_t base = (((((size_t)((b * 8 + h) * 32 + ktile)) * 4 + n) * 2 + (m >> 1)) * 4 + lh) * 128
                      + l16 * 8 + (m & 1) * 4;
        *(u32x2*)&vT[base] = pk2;
      }
    }
  }
}

// --- Kernel 4: LDS-free flash attention (fragment-direct global loads, no barriers) ---
__launch_bounds__(256, 2)
__global__ void attn_kernel(const short* __restrict__ q, const short* __restrict__ kT,
                            const short* __restrict__ vT, const short* __restrict__ flagsg,
                            const int* __restrict__ exist, short* __restrict__ att) {
  // XCD swizzle: all 16 q-blocks of one (b,h) land on the same XCD (id mod 8)
  int bx = blockIdx.x;                      // 0..1023
  int bh = ((bx >> 7) << 3) | (bx & 7);     // 0..63
  int qblk = (bx >> 3) & 15;
  int b = bh >> 3, h = bh & 7;
  int tid = threadIdx.x, wave = tid >> 6, lane = tid & 63;
  int l16 = lane & 15, lh = lane >> 4;
  int q0 = qblk * 128 + wave * 32;
  const short* qp = q + (size_t)bh * N_ * 64;
  const short* kpt = kT + (size_t)bh * 131072;   // 32 kt-tiles x 4096 shorts
  const short* vpt = vT + (size_t)bh * 131072;
  const short* fpt = flagsg + b * N_;
  const int* ex = exist + b * N_;
  v8s qf[2][2];
#pragma unroll
  for (int m = 0; m < 2; ++m)
#pragma unroll
    for (int kc = 0; kc < 2; ++kc)
      qf[m][kc] = *(const v8s*)&qp[(size_t)(q0 + m * 16 + l16) * 64 + kc * 32 + lh * 8];
  f32x4 oacc[2][4] = {};
  f32x4 lacc[2] = {};
  const f32x4 zf = {0.f, 0.f, 0.f, 0.f};
  int voff = lane * 8;                      // shorts: lane*16B
  v8s kf[8], vf[8], ff[2];
#pragma unroll
  for (int i = 0; i < 8; ++i) {
    kf[i] = *(const v8s*)&kpt[i * 512 + voff];
    vf[i] = *(const v8s*)&vpt[i * 512 + voff];
  }
  ff[0] = *(const v8s*)&fpt[lh * 8];
  ff[1] = *(const v8s*)&fpt[32 + lh * 8];
#pragma unroll 1
  for (int kt = 0; kt < 32; ++kt) {
    const short* kn = kpt + (size_t)(kt + 1) * 4096;   // next tile (last iter reads junk, unused)
    const short* vn = vpt + (size_t)(kt + 1) * 4096;
    const short* fn = fpt + (kt + 1) * 64;
    // ---- S^T = K @ Q  (base-2 exponents; lane: q=l16, kv=n*16+lh*4+r) ----
    f32x4 sacc[2][4];
#pragma unroll
    for (int n = 0; n < 4; ++n)
#pragma unroll
      for (int m = 0; m < 2; ++m) {
        sacc[m][n] = __builtin_amdgcn_mfma_f32_16x16x32_bf16(kf[n * 2], qf[m][0], zf, 0, 0, 0);
        sacc[m][n] = __builtin_amdgcn_mfma_f32_16x16x32_bf16(kf[n * 2 + 1], qf[m][1], sacc[m][n], 0, 0, 0);
      }
    // reload K fragments for next tile (WAR-safe: issued after consuming MFMAs)
#pragma unroll
    for (int i = 0; i < 8; ++i) kf[i] = *(const v8s*)&kn[i * 512 + voff];
    // ---- p = 2^s in-register -> PV A-fragments ----
    v8s pf[2][2];
#pragma unroll
    for (int m = 0; m < 2; ++m)
#pragma unroll
      for (int kc = 0; kc < 2; ++kc)
#pragma unroll
        for (int half = 0; half < 2; ++half) {
          int n = kc * 2 + half;
          float p0 = exp2f(sacc[m][n][0]);
          float p1 = exp2f(sacc[m][n][1]);
          float p2 = exp2f(sacc[m][n][2]);
          float p3 = exp2f(sacc[m][n][3]);
          uint w0, w1;
          asm("v_cvt_pk_bf16_f32 %0, %1, %2" : "=v"(w0) : "v"(p0), "v"(p1));
          asm("v_cvt_pk_bf16_f32 %0, %1, %2" : "=v"(w1) : "v"(p2), "v"(p3));
          ((uint*)&pf[m][kc])[half * 2]     = w0;
          ((uint*)&pf[m][kc])[half * 2 + 1] = w1;
        }
    // ---- O += P @ V ; l += P @ flag ----
#pragma unroll
    for (int kc = 0; kc < 2; ++kc) {
#pragma unroll
      for (int m = 0; m < 2; ++m)
        lacc[m] = __builtin_amdgcn_mfma_f32_16x16x32_bf16(pf[m][kc], ff[kc], lacc[m], 0, 0, 0);
#pragma unroll
      for (int n = 0; n < 4; ++n)
#pragma unroll
        for (int m = 0; m < 2; ++m)
          oacc[m][n] = __builtin_amdgcn_mfma_f32_16x16x32_bf16(pf[m][kc], vf[n * 2 + kc], oacc[m][n], 0, 0, 0);
    }
    // reload V + flag fragments for next tile
#pragma unroll
    for (int i = 0; i < 8; ++i) vf[i] = *(const v8s*)&vn[i * 512 + voff];
    ff[0] = *(const v8s*)&fn[lh * 8];
    ff[1] = *(const v8s*)&fn[32 + lh * 8];
  }
  // ---- epilogue: normalize, query-mask, write att[b][n][h*64+d] ----
#pragma unroll
  for (int m = 0; m < 2; ++m)
#pragma unroll
    for (int r = 0; r < 4; ++r) {
      int row = q0 + m * 16 + lh * 4 + r;
      float qm = (ex[row] != 0) ? 1.f : 0.f;
      float inv = qm / fmaxf(lacc[m][r], 1e-20f);
#pragma unroll
      for (int n = 0; n < 4; ++n)
        att[((size_t)(b * N_ + row)) * 512 + h * 64 + n * 16 + l16] = f2b(oacc[m][n][r] * inv);
    }
}

// ---------------- Kernel 5: out = att @ Wfc + bfc (M=16384, N=64, K=512), fp32 out ----------
__launch_bounds__(256)
__global__ void out_gemm(const short* __restrict__ att, const short* __restrict__ WfcT,
                         const float* __restrict__ bfc, float* __restrict__ out) {
  __shared__ short As[128][40];
  __shared__ short Bs[64][40];
  int bm = blockIdx.x;
  int tid = threadIdx.x, wave = tid >> 6, lane = tid & 63;
  int l16 = lane & 15, lh = lane >> 4;
  f32x4 acc[2][4] = {};
  for (int kt = 0; kt < 16; ++kt) {
    int k0 = kt * 32;
#pragma unroll
    for (int s = 0; s < 2; ++s) {
      int c = tid + s * 256;
      int r = c >> 2, c8 = c & 3;
      *(v8s*)&As[r][c8 * 8] = *(const v8s*)&att[(size_t)(bm * 128 + r) * 512 + k0 + c8 * 8];
    }
    { int r = tid >> 2, c8 = tid & 3;
      if (r < 64) *(v8s*)&Bs[r][c8 * 8] = *(const v8s*)&WfcT[(size_t)r * 512 + k0 + c8 * 8]; }
    __syncthreads();
    v8s bfr[4];
#pragma unroll
    for (int n = 0; n < 4; ++n) bfr[n] = *(const v8s*)&Bs[n * 16 + l16][lh * 8];
#pragma unroll
    for (int m = 0; m < 2; ++m) {
      v8s af = *(const v8s*)&As[wave * 32 + m * 16 + l16][lh * 8];
#pragma unroll
      for (int n = 0; n < 4; ++n)
        acc[m][n] = __builtin_amdgcn_mfma_f32_16x16x32_bf16(af, bfr[n], acc[m][n], 0, 0, 0);
    }
    __syncthreads();
  }
#pragma unroll
  for (int m = 0; m < 2; ++m)
#pragma unroll
    for (int n = 0; n < 4; ++n) {
      float bb = bfc[n * 16 + l16];
#pragma unroll
      for (int r = 0; r < 4; ++r) {
        int row = bm * 128 + wave * 32 + m * 16 + lh * 4 + r;
        out[(size_t)row * 64 + n * 16 + l16] = acc[m][n][r] + bb;
      }
    }
}

extern "C" void kernel_launch(void* const* d_in, const int* in_sizes, int n_in,
                              void* d_out, int out_size, void* d_ws, size_t ws_size,
                              hipStream_t stream) {
  const float* times = (const float*)d_in[0];
  const float* data  = (const float*)d_in[1];
  const float* maskv = (const float*)d_in[2];
  const int*   exist = (const int*)d_in[3];
  const float* w_per = (const float*)d_in[4];
  const float* b_per = (const float*)d_in[5];
  const float* w_lin = (const float*)d_in[6];
  const float* b_lin = (const float*)d_in[7];
  const float* Wq  = (const float*)d_in[8];
  const float* bq  = (const float*)d_in[9];
  const float* Wk  = (const float*)d_in[10];
  const float* bk  = (const float*)d_in[11];
  const float* Wv  = (const float*)d_in[12];
  const float* bv  = (const float*)d_in[13];
  const float* Wfc = (const float*)d_in[14];
  const float* bfc = (const float*)d_in[15];
  float* out = (float*)d_out;

  char* ws = (char*)d_ws;
  short* x     = (short*)(ws);                    // 16384*320*2  = 10,485,760
  short* Wt    = (short*)(ws + 10485760);         // 1536*320*2   =    983,040
  short* WfcT  = (short*)(ws + 11468800);         // 64*512*2     =     65,536
  short* qb    = (short*)(ws + 11534336);         // 64*2048*64*2 = 16,777,216
  short* kTb   = (short*)(ws + 28311552);         // K' fragment-major, 16 MB
  short* vTb   = (short*)(ws + 45088768);         // V' fragment-major, 16 MB
  short* att   = (short*)(ws + 61865984);         // 16384*512*2  = 16,777,216
  short* flagsg= (short*)(ws + 78643200);         // 16384+64 shorts (~33 KB)

  build_x<<<BN, 128, 0, stream>>>(times, data, maskv, w_per, b_per, w_lin, b_lin, exist, x, flagsg);
  transpose_w<<<2048, 256, 0, stream>>>(Wq, Wk, Wv, Wfc, Wt, WfcT);
  qkv_gemm<<<dim3(128, 12), 256, 0, stream>>>(x, Wt, bq, bk, bv, exist, qb, kTb, vTb);
  attn_kernel<<<1024, 256, 0, stream>>>(qb, kTb, vTb, flagsg, exist, att);
  out_gemm<<<128, 256, 0, stream>>>(att, WfcT, bfc, out);
}

// Round 9
// 154.375 us; speedup vs baseline: 1.0127x; 1.0060x over previous
//
#include <hip/hip_runtime.h>

#define N_ 2048
#define BN 16384
#define IN_DIM 320
#define QKV_N 1536
// (1/sqrt(320)) * log2(e): folded into Q so QK^T scores are base-2 exponents
#define ALPHA 0.08064911f

typedef float f32x4 __attribute__((ext_vector_type(4)));
typedef short v8s __attribute__((ext_vector_type(8)));
typedef unsigned int u32x2 __attribute__((ext_vector_type(2)));

__device__ __forceinline__ short f2b(float f) {
  unsigned u = __builtin_bit_cast(unsigned, f);
  u = u + 0x7fff + ((u >> 16) & 1);
  return (short)(u >> 16);
}

// pi permutation of kv within a 64-tile (matches S^T lane layout -> PV A-frag slots)
__device__ __forceinline__ int piperm(int t) {
  return ((t >> 5) & 1) * 32 + ((t >> 2) & 3) * 8 + ((t >> 4) & 1) * 4 + (t & 3);
}

// ---------------- Kernel 1: build x = [data | mask | time-embedding] + mask flags ------
__global__ void build_x(const float* __restrict__ times, const float* __restrict__ data,
                        const float* __restrict__ maskv, const float* __restrict__ w_per,
                        const float* __restrict__ b_per, const float* __restrict__ w_lin,
                        const float* __restrict__ b_lin, const int* __restrict__ exist,
                        short* __restrict__ x, short* __restrict__ flagsg) {
  int row = blockIdx.x;       // 0..16383
  int t = threadIdx.x;        // 128 threads
  float tt = times[row];
  short* xr = x + (size_t)row * IN_DIM;
  const float* dr = data + (size_t)row * 96;
  const float* mr = maskv + (size_t)row * 96;
  if (t < 96) { xr[t] = f2b(dr[t]); xr[96 + t] = f2b(mr[t]); }
  float val;
  if (t == 0) {
    val = tt * w_lin[0] + b_lin[0];
    // bf16 mask flag at pi-permuted position (row&~63 preserves b*2048 + tile base)
    flagsg[(row & ~63) | piperm(row & 63)] = (exist[row] != 0) ? (short)0x3F80 : (short)0;
  } else {
    val = __sinf(tt * w_per[t - 1] + b_per[t - 1]);
  }
  xr[192 + t] = f2b(val);
}

// ---------------- Kernel 2: transpose weights (fp32 -> bf16) ----------------
__global__ void transpose_w(const float* __restrict__ Wq, const float* __restrict__ Wk,
                            const float* __restrict__ Wv, const float* __restrict__ Wfc,
                            short* __restrict__ Wt, short* __restrict__ WfcT) {
  int idx = blockIdx.x * 256 + threadIdx.x;
  if (idx < QKV_N * IN_DIM) {
    int n = idx / IN_DIM, kk = idx - n * IN_DIM;
    const float* W = (n < 512) ? Wq : (n < 1024 ? Wk : Wv);
    Wt[idx] = f2b(W[(size_t)kk * 512 + (n & 511)]);
  } else {
    int j = idx - QKV_N * IN_DIM;   // 0..32767
    int d = j >> 9, kk = j & 511;
    WfcT[j] = f2b(Wfc[kk * 64 + d]);
  }
}

// ---------------- Kernel 3: QKV GEMM (M=16384, N=1536, K=320) ----------------
// q -> [bh][n][d]; K -> fragment-major K'; V -> fragment-major V' (pi-permuted, masked)
__launch_bounds__(256)
__global__ void qkv_gemm(const short* __restrict__ x, const short* __restrict__ Wt,
                         const float* __restrict__ bq, const float* __restrict__ bk,
                         const float* __restrict__ bv, const int* __restrict__ exist,
                         short* __restrict__ q, short* __restrict__ kT, short* __restrict__ vT) {
  __shared__ short As[128][40];
  __shared__ short Bs[128][40];
  int bm = blockIdx.x;   // 0..127
  int bn = blockIdx.y;   // 0..11
  int tid = threadIdx.x, wave = tid >> 6, lane = tid & 63;
  int wm = wave >> 1, wn = wave & 1;
  int l16 = lane & 15, lh = lane >> 4;
  f32x4 acc[4][4] = {};
  for (int kt = 0; kt < 10; ++kt) {
    int k0 = kt * 32;
#pragma unroll
    for (int s = 0; s < 2; ++s) {
      int c = tid + s * 256;          // 512 16B-chunks
      int r = c >> 2, c8 = c & 3;
      *(v8s*)&As[r][c8 * 8] = *(const v8s*)&x[(size_t)(bm * 128 + r) * IN_DIM + k0 + c8 * 8];
      *(v8s*)&Bs[r][c8 * 8] = *(const v8s*)&Wt[(size_t)(bn * 128 + r) * IN_DIM + k0 + c8 * 8];
    }
    __syncthreads();
    v8s af[4], bfr[4];
#pragma unroll
    for (int m = 0; m < 4; ++m) af[m] = *(const v8s*)&As[wm * 64 + m * 16 + l16][lh * 8];
#pragma unroll
    for (int n = 0; n < 4; ++n) bfr[n] = *(const v8s*)&Bs[wn * 64 + n * 16 + l16][lh * 8];
#pragma unroll
    for (int m = 0; m < 4; ++m)
#pragma unroll
      for (int n = 0; n < 4; ++n)
        acc[m][n] = __builtin_amdgcn_mfma_f32_16x16x32_bf16(af[m], bfr[n], acc[m][n], 0, 0, 0);
    __syncthreads();
  }
  int w = bn >> 2;   // 0:q 1:k 2:v (uniform per block)
  if (w == 0) {
#pragma unroll
    for (int m = 0; m < 4; ++m) {
      int row0 = bm * 128 + wm * 64 + m * 16 + lh * 4;
#pragma unroll
      for (int n = 0; n < 4; ++n) {
        int c = (bn * 128 + wn * 64 + n * 16 + l16) & 511;
        float bb = bq[c];
        int h = c >> 6, d = c & 63;
#pragma unroll
        for (int r = 0; r < 4; ++r) {
          int rr = row0 + r;
          int b = rr >> 11, ntok = rr & 2047;
          q[(((size_t)(b * 8 + h) * N_ + ntok) << 6) + d] = f2b((acc[m][n][r] + bb) * ALPHA);
        }
      }
    }
  } else if (w == 1) {
    // K' fragment-major: [bh][kt][m(kv-blk)][kc][lh2][l16'][8]
    int ktile = (bm * 2 + wm) & 31;         // = ntok >> 6 (m-independent)
    int b = bm >> 4;
#pragma unroll
    for (int m = 0; m < 4; ++m) {
#pragma unroll
      for (int n = 0; n < 4; ++n) {
        int c = (bn * 128 + wn * 64 + n * 16 + l16) & 511;
        float bb = bk[c];
        int h = c >> 6;
        int d = n * 16 + l16;               // == c & 63
        int kc2 = d >> 5, lh2 = (d >> 3) & 3, j = d & 7;
        size_t base = (((((size_t)((b * 8 + h) * 32 + ktile)) * 4 + m) * 2 + kc2) * 4 + lh2) * 128 + j;
#pragma unroll
        for (int r = 0; r < 4; ++r)
          kT[base + (lh * 4 + r) * 8] = f2b(acc[m][n][r] + bb);
      }
    }
  } else {
    // V' fragment-major: [bh][kt][n(d-blk)][kc=m>>1][lh][l16][8], pi slot (m&1)*4+r, masked
    int ktile = (bm * 2 + wm) & 31;
    int b = bm >> 4;
#pragma unroll
    for (int m = 0; m < 4; ++m) {
      int row0 = bm * 128 + wm * 64 + m * 16 + lh * 4;
      float fl[4];
#pragma unroll
      for (int r = 0; r < 4; ++r) fl[r] = (exist[row0 + r] != 0) ? 1.f : 0.f;
#pragma unroll
      for (int n = 0; n < 4; ++n) {
        int c = (bn * 128 + wn * 64 + n * 16 + l16) & 511;
        float bb = bv[c];
        int h = c >> 6;
        float v0 = (acc[m][n][0] + bb) * fl[0];
        float v1 = (acc[m][n][1] + bb) * fl[1];
        float v2 = (acc[m][n][2] + bb) * fl[2];
        float v3 = (acc[m][n][3] + bb) * fl[3];
        uint lopk, hipk;
        asm("v_cvt_pk_bf16_f32 %0, %1, %2" : "=v"(lopk) : "v"(v0), "v"(v1));
        asm("v_cvt_pk_bf16_f32 %0, %1, %2" : "=v"(hipk) : "v"(v2), "v"(v3));
        u32x2 pk2 = {lopk, hipk};
        size_t base = (((((size_t)((b * 8 + h) * 32 + ktile)) * 4 + n) * 2 + (m >> 1)) * 4 + lh) * 128
                      + l16 * 8 + (m & 1) * 4;
        *(u32x2*)&vT[base] = pk2;
      }
    }
  }
}

// --- Kernel 4: LDS-free flash attention, 64 q-rows/wave (fragment-direct, no barriers) ---
__launch_bounds__(256, 2)
__global__ void attn_kernel(const short* __restrict__ q, const short* __restrict__ kT,
                            const short* __restrict__ vT, const short* __restrict__ flagsg,
                            const int* __restrict__ exist, short* __restrict__ att) {
  // XCD swizzle: all 8 q-blocks of one (b,h) land on the same XCD (id mod 8)
  int bx = blockIdx.x;                      // 0..511
  int bh = ((bx >> 6) << 3) | (bx & 7);     // 0..63
  int qblk = (bx >> 3) & 7;
  int b = bh >> 3, h = bh & 7;
  int tid = threadIdx.x, wave = tid >> 6, lane = tid & 63;
  int l16 = lane & 15, lh = lane >> 4;
  int q0 = qblk * 256 + wave * 64;
  const short* qp = q + (size_t)bh * N_ * 64;
  const short* kpt = kT + (size_t)bh * 131072;   // 32 kt-tiles x 4096 shorts
  const short* vpt = vT + (size_t)bh * 131072;
  const short* fpt = flagsg + b * N_;
  const int* ex = exist + b * N_;
  v8s qf[4][2];
#pragma unroll
  for (int m = 0; m < 4; ++m)
#pragma unroll
    for (int kc = 0; kc < 2; ++kc)
      qf[m][kc] = *(const v8s*)&qp[(size_t)(q0 + m * 16 + l16) * 64 + kc * 32 + lh * 8];
  f32x4 oacc[4][4] = {};
  f32x4 lacc[4] = {};
  const f32x4 zf = {0.f, 0.f, 0.f, 0.f};
  int voff = lane * 8;                      // shorts: lane*16B
  v8s kf[8], vf[8], ff[2];
#pragma unroll
  for (int i = 0; i < 8; ++i) {
    kf[i] = *(const v8s*)&kpt[i * 512 + voff];
    vf[i] = *(const v8s*)&vpt[i * 512 + voff];
  }
  ff[0] = *(const v8s*)&fpt[lh * 8];
  ff[1] = *(const v8s*)&fpt[32 + lh * 8];
#pragma unroll 1
  for (int kt = 0; kt < 32; ++kt) {
    const short* kn = kpt + (size_t)(kt + 1) * 4096;   // next tile (last iter reads junk, unused)
    const short* vn = vpt + (size_t)(kt + 1) * 4096;
    const short* fn = fpt + (kt + 1) * 64;
    // ---- process m-halves serially to cap register pressure ----
#pragma unroll
    for (int mh = 0; mh < 2; ++mh) {
      // S^T = K @ Q for 2 m's (base-2 exponents; lane: q=l16, kv=n*16+lh*4+r)
      f32x4 sacc[2][4];
#pragma unroll
      for (int n = 0; n < 4; ++n)
#pragma unroll
        for (int mm = 0; mm < 2; ++mm) {
          sacc[mm][n] = __builtin_amdgcn_mfma_f32_16x16x32_bf16(kf[n * 2], qf[mh * 2 + mm][0], zf, 0, 0, 0);
          sacc[mm][n] = __builtin_amdgcn_mfma_f32_16x16x32_bf16(kf[n * 2 + 1], qf[mh * 2 + mm][1], sacc[mm][n], 0, 0, 0);
        }
      // after the last kf use (mh==1 QKT), reload K fragments for next tile
      if (mh == 1)
#pragma unroll
        for (int i = 0; i < 8; ++i) kf[i] = *(const v8s*)&kn[i * 512 + voff];
      // p = 2^s in-register -> PV A-fragments
      v8s pf[2][2];
#pragma unroll
      for (int mm = 0; mm < 2; ++mm)
#pragma unroll
        for (int kc = 0; kc < 2; ++kc)
#pragma unroll
          for (int half = 0; half < 2; ++half) {
            int n = kc * 2 + half;
            float p0 = exp2f(sacc[mm][n][0]);
            float p1 = exp2f(sacc[mm][n][1]);
            float p2 = exp2f(sacc[mm][n][2]);
            float p3 = exp2f(sacc[mm][n][3]);
            uint w0, w1;
            asm("v_cvt_pk_bf16_f32 %0, %1, %2" : "=v"(w0) : "v"(p0), "v"(p1));
            asm("v_cvt_pk_bf16_f32 %0, %1, %2" : "=v"(w1) : "v"(p2), "v"(p3));
            ((uint*)&pf[mm][kc])[half * 2]     = w0;
            ((uint*)&pf[mm][kc])[half * 2 + 1] = w1;
          }
      // O += P @ V ; l += P @ flag
#pragma unroll
      for (int kc = 0; kc < 2; ++kc) {
#pragma unroll
        for (int mm = 0; mm < 2; ++mm)
          lacc[mh * 2 + mm] = __builtin_amdgcn_mfma_f32_16x16x32_bf16(pf[mm][kc], ff[kc], lacc[mh * 2 + mm], 0, 0, 0);
#pragma unroll
        for (int n = 0; n < 4; ++n)
#pragma unroll
          for (int mm = 0; mm < 2; ++mm)
            oacc[mh * 2 + mm][n] = __builtin_amdgcn_mfma_f32_16x16x32_bf16(pf[mm][kc], vf[n * 2 + kc], oacc[mh * 2 + mm][n], 0, 0, 0);
      }
    }
    // reload V + flag fragments for next tile (after last vf/ff use)
#pragma unroll
    for (int i = 0; i < 8; ++i) vf[i] = *(const v8s*)&vn[i * 512 + voff];
    ff[0] = *(const v8s*)&fn[lh * 8];
    ff[1] = *(const v8s*)&fn[32 + lh * 8];
  }
  // ---- epilogue: normalize, query-mask, write att[b][n][h*64+d] ----
#pragma unroll
  for (int m = 0; m < 4; ++m)
#pragma unroll
    for (int r = 0; r < 4; ++r) {
      int row = q0 + m * 16 + lh * 4 + r;
      float qm = (ex[row] != 0) ? 1.f : 0.f;
      float inv = qm / fmaxf(lacc[m][r], 1e-20f);
#pragma unroll
      for (int n = 0; n < 4; ++n)
        att[((size_t)(b * N_ + row)) * 512 + h * 64 + n * 16 + l16] = f2b(oacc[m][n][r] * inv);
    }
}

// ---------------- Kernel 5: out = att @ Wfc + bfc (M=16384, N=64, K=512), fp32 out ----------
__launch_bounds__(256)
__global__ void out_gemm(const short* __restrict__ att, const short* __restrict__ WfcT,
                         const float* __restrict__ bfc, float* __restrict__ out) {
  __shared__ short As[128][40];
  __shared__ short Bs[64][40];
  int bm = blockIdx.x;
  int tid = threadIdx.x, wave = tid >> 6, lane = tid & 63;
  int l16 = lane & 15, lh = lane >> 4;
  f32x4 acc[2][4] = {};
  for (int kt = 0; kt < 16; ++kt) {
    int k0 = kt * 32;
#pragma unroll
    for (int s = 0; s < 2; ++s) {
      int c = tid + s * 256;
      int r = c >> 2, c8 = c & 3;
      *(v8s*)&As[r][c8 * 8] = *(const v8s*)&att[(size_t)(bm * 128 + r) * 512 + k0 + c8 * 8];
    }
    { int r = tid >> 2, c8 = tid & 3;
      if (r < 64) *(v8s*)&Bs[r][c8 * 8] = *(const v8s*)&WfcT[(size_t)r * 512 + k0 + c8 * 8]; }
    __syncthreads();
    v8s bfr[4];
#pragma unroll
    for (int n = 0; n < 4; ++n) bfr[n] = *(const v8s*)&Bs[n * 16 + l16][lh * 8];
#pragma unroll
    for (int m = 0; m < 2; ++m) {
      v8s af = *(const v8s*)&As[wave * 32 + m * 16 + l16][lh * 8];
#pragma unroll
      for (int n = 0; n < 4; ++n)
        acc[m][n] = __builtin_amdgcn_mfma_f32_16x16x32_bf16(af, bfr[n], acc[m][n], 0, 0, 0);
    }
    __syncthreads();
  }
#pragma unroll
  for (int m = 0; m < 2; ++m)
#pragma unroll
    for (int n = 0; n < 4; ++n) {
      float bb = bfc[n * 16 + l16];
#pragma unroll
      for (int r = 0; r < 4; ++r) {
        int row = bm * 128 + wave * 32 + m * 16 + lh * 4 + r;
        out[(size_t)row * 64 + n * 16 + l16] = acc[m][n][r] + bb;
      }
    }
}

extern "C" void kernel_launch(void* const* d_in, const int* in_sizes, int n_in,
                              void* d_out, int out_size, void* d_ws, size_t ws_size,
                              hipStream_t stream) {
  const float* times = (const float*)d_in[0];
  const float* data  = (const float*)d_in[1];
  const float* maskv = (const float*)d_in[2];
  const int*   exist = (const int*)d_in[3];
  const float* w_per = (const float*)d_in[4];
  const float* b_per = (const float*)d_in[5];
  const float* w_lin = (const float*)d_in[6];
  const float* b_lin = (const float*)d_in[7];
  const float* Wq  = (const float*)d_in[8];
  const float* bq  = (const float*)d_in[9];
  const float* Wk  = (const float*)d_in[10];
  const float* bk  = (const float*)d_in[11];
  const float* Wv  = (const float*)d_in[12];
  const float* bv  = (const float*)d_in[13];
  const float* Wfc = (const float*)d_in[14];
  const float* bfc = (const float*)d_in[15];
  float* out = (float*)d_out;

  char* ws = (char*)d_ws;
  short* x     = (short*)(ws);                    // 16384*320*2  = 10,485,760
  short* Wt    = (short*)(ws + 10485760);         // 1536*320*2   =    983,040
  short* WfcT  = (short*)(ws + 11468800);         // 64*512*2     =     65,536
  short* qb    = (short*)(ws + 11534336);         // 64*2048*64*2 = 16,777,216
  short* kTb   = (short*)(ws + 28311552);         // K' fragment-major, 16 MB
  short* vTb   = (short*)(ws + 45088768);         // V' fragment-major, 16 MB
  short* att   = (short*)(ws + 61865984);         // 16384*512*2  = 16,777,216
  short* flagsg= (short*)(ws + 78643200);         // 16384+64 shorts (~33 KB)

  build_x<<<BN, 128, 0, stream>>>(times, data, maskv, w_per, b_per, w_lin, b_lin, exist, x, flagsg);
  transpose_w<<<2048, 256, 0, stream>>>(Wq, Wk, Wv, Wfc, Wt, WfcT);
  qkv_gemm<<<dim3(128, 12), 256, 0, stream>>>(x, Wt, bq, bk, bv, exist, qb, kTb, vTb);
  attn_kernel<<<512, 256, 0, stream>>>(qb, kTb, vTb, flagsg, exist, att);
  out_gemm<<<128, 256, 0, stream>>>(att, WfcT, bfc, out);
}

// Round 10
// 125.116 us; speedup vs baseline: 1.2495x; 1.2338x over previous
//
#include <hip/hip_runtime.h>

#define N_ 2048
#define BN 16384
#define IN_DIM 320
#define QKV_N 1536
// (1/sqrt(320)) * log2(e): folded into Q so QK^T scores are base-2 exponents
#define ALPHA 0.08064911f

typedef float f32x4 __attribute__((ext_vector_type(4)));
typedef short v8s __attribute__((ext_vector_type(8)));
typedef unsigned int u32x2 __attribute__((ext_vector_type(2)));

__device__ __forceinline__ short f2b(float f) {
  unsigned u = __builtin_bit_cast(unsigned, f);
  u = u + 0x7fff + ((u >> 16) & 1);
  return (short)(u >> 16);
}

// pi permutation of kv within a 64-tile (matches S^T lane layout -> PV A-frag slots)
__device__ __forceinline__ int piperm(int t) {
  return ((t >> 5) & 1) * 32 + ((t >> 2) & 3) * 8 + ((t >> 4) & 1) * 4 + (t & 3);
}

// ---------------- Kernel 1: build x = [data | mask | time-embedding] + mask flags ------
__global__ void build_x(const float* __restrict__ times, const float* __restrict__ data,
                        const float* __restrict__ maskv, const float* __restrict__ w_per,
                        const float* __restrict__ b_per, const float* __restrict__ w_lin,
                        const float* __restrict__ b_lin, const int* __restrict__ exist,
                        short* __restrict__ x, short* __restrict__ flagsg) {
  int row = blockIdx.x;       // 0..16383
  int t = threadIdx.x;        // 128 threads
  float tt = times[row];
  short* xr = x + (size_t)row * IN_DIM;
  const float* dr = data + (size_t)row * 96;
  const float* mr = maskv + (size_t)row * 96;
  if (t < 96) { xr[t] = f2b(dr[t]); xr[96 + t] = f2b(mr[t]); }
  float val;
  if (t == 0) {
    val = tt * w_lin[0] + b_lin[0];
    // bf16 mask flag at pi-permuted position (row&~63 preserves b*2048 + tile base)
    flagsg[(row & ~63) | piperm(row & 63)] = (exist[row] != 0) ? (short)0x3F80 : (short)0;
  } else {
    val = __sinf(tt * w_per[t - 1] + b_per[t - 1]);
  }
  xr[192 + t] = f2b(val);
}

// ---------------- Kernel 2: transpose weights (fp32 -> bf16) ----------------
__global__ void transpose_w(const float* __restrict__ Wq, const float* __restrict__ Wk,
                            const float* __restrict__ Wv, const float* __restrict__ Wfc,
                            short* __restrict__ Wt, short* __restrict__ WfcT) {
  int idx = blockIdx.x * 256 + threadIdx.x;
  if (idx < QKV_N * IN_DIM) {
    int n = idx / IN_DIM, kk = idx - n * IN_DIM;
    const float* W = (n < 512) ? Wq : (n < 1024 ? Wk : Wv);
    Wt[idx] = f2b(W[(size_t)kk * 512 + (n & 511)]);
  } else {
    int j = idx - QKV_N * IN_DIM;   // 0..32767
    int d = j >> 9, kk = j & 511;
    WfcT[j] = f2b(Wfc[kk * 64 + d]);
  }
}

// ---------------- Kernel 3: QKV GEMM (M=16384, N=1536, K=320) ----------------
// q -> [bh][n][d]; K -> fragment-major K'; V -> fragment-major V' (pi-permuted, masked)
__launch_bounds__(256)
__global__ void qkv_gemm(const short* __restrict__ x, const short* __restrict__ Wt,
                         const float* __restrict__ bq, const float* __restrict__ bk,
                         const float* __restrict__ bv, const int* __restrict__ exist,
                         short* __restrict__ q, short* __restrict__ kT, short* __restrict__ vT) {
  __shared__ short As[128][40];
  __shared__ short Bs[128][40];
  int bm = blockIdx.x;   // 0..127
  int bn = blockIdx.y;   // 0..11
  int tid = threadIdx.x, wave = tid >> 6, lane = tid & 63;
  int wm = wave >> 1, wn = wave & 1;
  int l16 = lane & 15, lh = lane >> 4;
  f32x4 acc[4][4] = {};
  for (int kt = 0; kt < 10; ++kt) {
    int k0 = kt * 32;
#pragma unroll
    for (int s = 0; s < 2; ++s) {
      int c = tid + s * 256;          // 512 16B-chunks
      int r = c >> 2, c8 = c & 3;
      *(v8s*)&As[r][c8 * 8] = *(const v8s*)&x[(size_t)(bm * 128 + r) * IN_DIM + k0 + c8 * 8];
      *(v8s*)&Bs[r][c8 * 8] = *(const v8s*)&Wt[(size_t)(bn * 128 + r) * IN_DIM + k0 + c8 * 8];
    }
    __syncthreads();
    v8s af[4], bfr[4];
#pragma unroll
    for (int m = 0; m < 4; ++m) af[m] = *(const v8s*)&As[wm * 64 + m * 16 + l16][lh * 8];
#pragma unroll
    for (int n = 0; n < 4; ++n) bfr[n] = *(const v8s*)&Bs[wn * 64 + n * 16 + l16][lh * 8];
#pragma unroll
    for (int m = 0; m < 4; ++m)
#pragma unroll
      for (int n = 0; n < 4; ++n)
        acc[m][n] = __builtin_amdgcn_mfma_f32_16x16x32_bf16(af[m], bfr[n], acc[m][n], 0, 0, 0);
    __syncthreads();
  }
  int w = bn >> 2;   // 0:q 1:k 2:v (uniform per block)
  if (w == 0) {
#pragma unroll
    for (int m = 0; m < 4; ++m) {
      int row0 = bm * 128 + wm * 64 + m * 16 + lh * 4;
#pragma unroll
      for (int n = 0; n < 4; ++n) {
        int c = (bn * 128 + wn * 64 + n * 16 + l16) & 511;
        float bb = bq[c];
        int h = c >> 6, d = c & 63;
#pragma unroll
        for (int r = 0; r < 4; ++r) {
          int rr = row0 + r;
          int b = rr >> 11, ntok = rr & 2047;
          q[(((size_t)(b * 8 + h) * N_ + ntok) << 6) + d] = f2b((acc[m][n][r] + bb) * ALPHA);
        }
      }
    }
  } else if (w == 1) {
    // K' fragment-major: [bh][kt][m(kv-blk)][kc][lh2][l16'][8]
    int ktile = (bm * 2 + wm) & 31;         // = ntok >> 6 (m-independent)
    int b = bm >> 4;
#pragma unroll
    for (int m = 0; m < 4; ++m) {
#pragma unroll
      for (int n = 0; n < 4; ++n) {
        int c = (bn * 128 + wn * 64 + n * 16 + l16) & 511;
        float bb = bk[c];
        int h = c >> 6;
        int d = n * 16 + l16;               // == c & 63
        int kc2 = d >> 5, lh2 = (d >> 3) & 3, j = d & 7;
        size_t base = (((((size_t)((b * 8 + h) * 32 + ktile)) * 4 + m) * 2 + kc2) * 4 + lh2) * 128 + j;
#pragma unroll
        for (int r = 0; r < 4; ++r)
          kT[base + (lh * 4 + r) * 8] = f2b(acc[m][n][r] + bb);
      }
    }
  } else {
    // V' fragment-major: [bh][kt][n(d-blk)][kc=m>>1][lh][l16][8], pi slot (m&1)*4+r, masked
    int ktile = (bm * 2 + wm) & 31;
    int b = bm >> 4;
#pragma unroll
    for (int m = 0; m < 4; ++m) {
      int row0 = bm * 128 + wm * 64 + m * 16 + lh * 4;
      float fl[4];
#pragma unroll
      for (int r = 0; r < 4; ++r) fl[r] = (exist[row0 + r] != 0) ? 1.f : 0.f;
#pragma unroll
      for (int n = 0; n < 4; ++n) {
        int c = (bn * 128 + wn * 64 + n * 16 + l16) & 511;
        float bb = bv[c];
        int h = c >> 6;
        float v0 = (acc[m][n][0] + bb) * fl[0];
        float v1 = (acc[m][n][1] + bb) * fl[1];
        float v2 = (acc[m][n][2] + bb) * fl[2];
        float v3 = (acc[m][n][3] + bb) * fl[3];
        uint lopk, hipk;
        asm("v_cvt_pk_bf16_f32 %0, %1, %2" : "=v"(lopk) : "v"(v0), "v"(v1));
        asm("v_cvt_pk_bf16_f32 %0, %1, %2" : "=v"(hipk) : "v"(v2), "v"(v3));
        u32x2 pk2 = {lopk, hipk};
        size_t base = (((((size_t)((b * 8 + h) * 32 + ktile)) * 4 + n) * 2 + (m >> 1)) * 4 + lh) * 128
                      + l16 * 8 + (m & 1) * 4;
        *(u32x2*)&vT[base] = pk2;
      }
    }
  }
}

// --- Kernel 4: LDS-free flash attention, 64 q-rows/wave (fragment-direct, no barriers) ---
__launch_bounds__(256, 2)
__global__ void attn_kernel(const short* __restrict__ q, const short* __restrict__ kT,
                            const short* __restrict__ vT, const short* __restrict__ flagsg,
                            const int* __restrict__ exist, short* __restrict__ att) {
  // XCD swizzle: all 8 q-blocks of one (b,h) land on the same XCD (id mod 8)
  int bx = blockIdx.x;                      // 0..511
  int bh = ((bx >> 6) << 3) | (bx & 7);     // 0..63
  int qblk = (bx >> 3) & 7;
  int b = bh >> 3, h = bh & 7;
  int tid = threadIdx.x, wave = tid >> 6, lane = tid & 63;
  int l16 = lane & 15, lh = lane >> 4;
  int q0 = qblk * 256 + wave * 64;
  const short* qp = q + (size_t)bh * N_ * 64;
  const short* kpt = kT + (size_t)bh * 131072;   // 32 kt-tiles x 4096 shorts
  const short* vpt = vT + (size_t)bh * 131072;
  const short* fpt = flagsg + b * N_;
  const int* ex = exist + b * N_;
  v8s qf[4][2];
#pragma unroll
  for (int m = 0; m < 4; ++m)
#pragma unroll
    for (int kc = 0; kc < 2; ++kc)
      qf[m][kc] = *(const v8s*)&qp[(size_t)(q0 + m * 16 + l16) * 64 + kc * 32 + lh * 8];
  f32x4 oacc[4][4] = {};
  f32x4 lacc[4] = {};
  const f32x4 zf = {0.f, 0.f, 0.f, 0.f};
  int voff = lane * 8;                      // shorts: lane*16B
  v8s kf[8], vf[8], ff[2];
#pragma unroll
  for (int i = 0; i < 8; ++i) {
    kf[i] = *(const v8s*)&kpt[i * 512 + voff];
    vf[i] = *(const v8s*)&vpt[i * 512 + voff];
  }
  ff[0] = *(const v8s*)&fpt[lh * 8];
  ff[1] = *(const v8s*)&fpt[32 + lh * 8];
#pragma unroll 1
  for (int kt = 0; kt < 32; ++kt) {
    const short* kn = kpt + (size_t)(kt + 1) * 4096;   // next tile (last iter reads junk, unused)
    const short* vn = vpt + (size_t)(kt + 1) * 4096;
    const short* fn = fpt + (kt + 1) * 64;
    // ---- process m-halves serially to cap register pressure ----
#pragma unroll
    for (int mh = 0; mh < 2; ++mh) {
      // S^T = K @ Q for 2 m's (base-2 exponents; lane: q=l16, kv=n*16+lh*4+r)
      f32x4 sacc[2][4];
#pragma unroll
      for (int n = 0; n < 4; ++n)
#pragma unroll
        for (int mm = 0; mm < 2; ++mm) {
          sacc[mm][n] = __builtin_amdgcn_mfma_f32_16x16x32_bf16(kf[n * 2], qf[mh * 2 + mm][0], zf, 0, 0, 0);
          sacc[mm][n] = __builtin_amdgcn_mfma_f32_16x16x32_bf16(kf[n * 2 + 1], qf[mh * 2 + mm][1], sacc[mm][n], 0, 0, 0);
        }
      // after the last kf use (mh==1 QKT), reload K fragments for next tile
      if (mh == 1)
#pragma unroll
        for (int i = 0; i < 8; ++i) kf[i] = *(const v8s*)&kn[i * 512 + voff];
      // p = 2^s in-register (raw v_exp_f32) -> PV A-fragments
      v8s pf[2][2];
#pragma unroll
      for (int mm = 0; mm < 2; ++mm)
#pragma unroll
        for (int kc = 0; kc < 2; ++kc)
#pragma unroll
          for (int half = 0; half < 2; ++half) {
            int n = kc * 2 + half;
            float p0 = __builtin_amdgcn_exp2f(sacc[mm][n][0]);
            float p1 = __builtin_amdgcn_exp2f(sacc[mm][n][1]);
            float p2 = __builtin_amdgcn_exp2f(sacc[mm][n][2]);
            float p3 = __builtin_amdgcn_exp2f(sacc[mm][n][3]);
            uint w0, w1;
            asm("v_cvt_pk_bf16_f32 %0, %1, %2" : "=v"(w0) : "v"(p0), "v"(p1));
            asm("v_cvt_pk_bf16_f32 %0, %1, %2" : "=v"(w1) : "v"(p2), "v"(p3));
            ((uint*)&pf[mm][kc])[half * 2]     = w0;
            ((uint*)&pf[mm][kc])[half * 2 + 1] = w1;
          }
      // O += P @ V ; l += P @ flag
#pragma unroll
      for (int kc = 0; kc < 2; ++kc) {
#pragma unroll
        for (int mm = 0; mm < 2; ++mm)
          lacc[mh * 2 + mm] = __builtin_amdgcn_mfma_f32_16x16x32_bf16(pf[mm][kc], ff[kc], lacc[mh * 2 + mm], 0, 0, 0);
#pragma unroll
        for (int n = 0; n < 4; ++n)
#pragma unroll
          for (int mm = 0; mm < 2; ++mm)
            oacc[mh * 2 + mm][n] = __builtin_amdgcn_mfma_f32_16x16x32_bf16(pf[mm][kc], vf[n * 2 + kc], oacc[mh * 2 + mm][n], 0, 0, 0);
      }
    }
    // reload V + flag fragments for next tile (after last vf/ff use)
#pragma unroll
    for (int i = 0; i < 8; ++i) vf[i] = *(const v8s*)&vn[i * 512 + voff];
    ff[0] = *(const v8s*)&fn[lh * 8];
    ff[1] = *(const v8s*)&fn[32 + lh * 8];
  }
  // ---- epilogue: normalize, query-mask, write att[b][n][h*64+d] ----
#pragma unroll
  for (int m = 0; m < 4; ++m)
#pragma unroll
    for (int r = 0; r < 4; ++r) {
      int row = q0 + m * 16 + lh * 4 + r;
      float qm = (ex[row] != 0) ? 1.f : 0.f;
      float inv = qm / fmaxf(lacc[m][r], 1e-20f);
#pragma unroll
      for (int n = 0; n < 4; ++n)
        att[((size_t)(b * N_ + row)) * 512 + h * 64 + n * 16 + l16] = f2b(oacc[m][n][r] * inv);
    }
}

// ---------------- Kernel 5: out = att @ Wfc + bfc (M=16384, N=64, K=512), fp32 out ----------
__launch_bounds__(256)
__global__ void out_gemm(const short* __restrict__ att, const short* __restrict__ WfcT,
                         const float* __restrict__ bfc, float* __restrict__ out) {
  __shared__ short As[128][40];
  __shared__ short Bs[64][40];
  int bm = blockIdx.x;
  int tid = threadIdx.x, wave = tid >> 6, lane = tid & 63;
  int l16 = lane & 15, lh = lane >> 4;
  f32x4 acc[2][4] = {};
  for (int kt = 0; kt < 16; ++kt) {
    int k0 = kt * 32;
#pragma unroll
    for (int s = 0; s < 2; ++s) {
      int c = tid + s * 256;
      int r = c >> 2, c8 = c & 3;
      *(v8s*)&As[r][c8 * 8] = *(const v8s*)&att[(size_t)(bm * 128 + r) * 512 + k0 + c8 * 8];
    }
    { int r = tid >> 2, c8 = tid & 3;
      if (r < 64) *(v8s*)&Bs[r][c8 * 8] = *(const v8s*)&WfcT[(size_t)r * 512 + k0 + c8 * 8]; }
    __syncthreads();
    v8s bfr[4];
#pragma unroll
    for (int n = 0; n < 4; ++n) bfr[n] = *(const v8s*)&Bs[n * 16 + l16][lh * 8];
#pragma unroll
    for (int m = 0; m < 2; ++m) {
      v8s af = *(const v8s*)&As[wave * 32 + m * 16 + l16][lh * 8];
#pragma unroll
      for (int n = 0; n < 4; ++n)
        acc[m][n] = __builtin_amdgcn_mfma_f32_16x16x32_bf16(af, bfr[n], acc[m][n], 0, 0, 0);
    }
    __syncthreads();
  }
#pragma unroll
  for (int m = 0; m < 2; ++m)
#pragma unroll
    for (int n = 0; n < 4; ++n) {
      float bb = bfc[n * 16 + l16];
#pragma unroll
      for (int r = 0; r < 4; ++r) {
        int row = bm * 128 + wave * 32 + m * 16 + lh * 4 + r;
        out[(size_t)row * 64 + n * 16 + l16] = acc[m][n][r] + bb;
      }
    }
}

extern "C" void kernel_launch(void* const* d_in, const int* in_sizes, int n_in,
                              void* d_out, int out_size, void* d_ws, size_t ws_size,
                              hipStream_t stream) {
  const float* times = (const float*)d_in[0];
  const float* data  = (const float*)d_in[1];
  const float* maskv = (const float*)d_in[2];
  const int*   exist = (const int*)d_in[3];
  const float* w_per = (const float*)d_in[4];
  const float* b_per = (const float*)d_in[5];
  const float* w_lin = (const float*)d_in[6];
  const float* b_lin = (const float*)d_in[7];
  const float* Wq  = (const float*)d_in[8];
  const float* bq  = (const float*)d_in[9];
  const float* Wk  = (const float*)d_in[10];
  const float* bk  = (const float*)d_in[11];
  const float* Wv  = (const float*)d_in[12];
  const float* bv  = (const float*)d_in[13];
  const float* Wfc = (const float*)d_in[14];
  const float* bfc = (const float*)d_in[15];
  float* out = (float*)d_out;

  char* ws = (char*)d_ws;
  short* x     = (short*)(ws);                    // 16384*320*2  = 10,485,760
  short* Wt    = (short*)(ws + 10485760);         // 1536*320*2   =    983,040
  short* WfcT  = (short*)(ws + 11468800);         // 64*512*2     =     65,536
  short* qb    = (short*)(ws + 11534336);         // 64*2048*64*2 = 16,777,216
  short* kTb   = (short*)(ws + 28311552);         // K' fragment-major, 16 MB
  short* vTb   = (short*)(ws + 45088768);         // V' fragment-major, 16 MB
  short* att   = (short*)(ws + 61865984);         // 16384*512*2  = 16,777,216
  short* flagsg= (short*)(ws + 78643200);         // 16384+64 shorts (~33 KB)

  build_x<<<BN, 128, 0, stream>>>(times, data, maskv, w_per, b_per, w_lin, b_lin, exist, x, flagsg);
  transpose_w<<<2048, 256, 0, stream>>>(Wq, Wk, Wv, Wfc, Wt, WfcT);
  qkv_gemm<<<dim3(128, 12), 256, 0, stream>>>(x, Wt, bq, bk, bv, exist, qb, kTb, vTb);
  attn_kernel<<<512, 256, 0, stream>>>(qb, kTb, vTb, flagsg, exist, att);
  out_gemm<<<128, 256, 0, stream>>>(att, WfcT, bfc, out);
}